// Round 1
// baseline (996.114 us; speedup 1.0000x reference)
//
#include <hip/hip_runtime.h>
#include <hip/hip_bf16.h>

// Exact tanh via exp: tanh(x) = sign(x) * (1-e)/(1+e), e = exp(-2|x|)
__device__ __forceinline__ float fast_tanh(float x) {
    float e = __expf(-2.0f * fabsf(x));
    float r = __fdividef(1.0f - e, 1.0f + e);
    return copysignf(r, x);
}

__device__ __forceinline__ float leaky(float x) {
    return x > 0.0f ? x : 0.01f * x;
}

// One thread per edge: gather -> [IN]x32 MLP -> leaky -> 32x64 -> tanh ->
// wave-level LDS transpose -> coalesced atomic scatter-add into accum[dst*64+j].
// IN = 5 + FEAT  (pos_src(2), pos_dst(2), dis(1), feat(FEAT))
template <int FEAT>
__global__ __launch_bounds__(256, 2) void edge_mlp_scatter(
    const float* __restrict__ pos_src_tbl,  // [*,2] indexed by src
    const float* __restrict__ pos_dst_tbl,  // [*,2] indexed by dst
    const float* __restrict__ dis,          // [E]
    const float* __restrict__ feat_tbl,     // [*,FEAT] indexed by src
    const int* __restrict__ src, const int* __restrict__ dst,
    const float* __restrict__ W1,  // [(5+FEAT), 32] row-major
    const float* __restrict__ b1,  // [32]
    const float* __restrict__ W2,  // [32, 64] row-major
    const float* __restrict__ b2,  // [64]
    float* __restrict__ accum,     // [N_S, 64]
    int E) {
    __shared__ float tr[4][16][65];  // [wave][chunk-channel][edge] (+pad)
    __shared__ int dstsh[4][64];     // dst row base per edge (or -1 invalid)

    const int tid = threadIdx.x;
    const int lane = tid & 63;
    const int wave = tid >> 6;
    const int e = blockIdx.x * 256 + tid;
    const bool valid = e < E;
    const int ee = valid ? e : (E - 1);

    const int s = src[ee];
    const int d = dst[ee];

    float f[5];
    f[0] = pos_src_tbl[2 * s];
    f[1] = pos_src_tbl[2 * s + 1];
    f[2] = pos_dst_tbl[2 * d];
    f[3] = pos_dst_tbl[2 * d + 1];
    f[4] = dis[ee];

    // ---- layer 1: hid = leaky(inp @ W1 + b1) ----
    float hid[32];
#pragma unroll
    for (int j = 0; j < 32; j++) hid[j] = b1[j];
#pragma unroll
    for (int k = 0; k < 5; k++) {
        const float v = f[k];
        const float* w = W1 + k * 32;
#pragma unroll
        for (int j = 0; j < 32; j++) hid[j] += v * w[j];
    }
    const float4* fp = reinterpret_cast<const float4*>(feat_tbl + s * FEAT);
#pragma unroll
    for (int c = 0; c < FEAT / 4; c++) {
        const float4 v = fp[c];
        const float* w = W1 + (5 + 4 * c) * 32;
#pragma unroll
        for (int j = 0; j < 32; j++) {
            hid[j] += v.x * w[j];
            hid[j] += v.y * w[32 + j];
            hid[j] += v.z * w[64 + j];
            hid[j] += v.w * w[96 + j];
        }
    }
#pragma unroll
    for (int j = 0; j < 32; j++) hid[j] = leaky(hid[j]);

    // ---- layer 2: out = tanh(hid @ W2 + b2) ----
    float out[64];
#pragma unroll
    for (int j = 0; j < 64; j++) out[j] = b2[j];
#pragma unroll
    for (int k = 0; k < 32; k++) {
        const float v = hid[k];
        const float* w = W2 + k * 64;
#pragma unroll
        for (int j = 0; j < 64; j++) out[j] += v * w[j];
    }
#pragma unroll
    for (int j = 0; j < 64; j++) out[j] = fast_tanh(out[j]);

    // ---- scatter: wave transpose in 16-channel chunks, coalesced atomics ----
    dstsh[wave][lane] = valid ? (d * 64) : -1;
    __syncthreads();
    const int ch = lane & 15;  // channel within chunk
    const int eo = lane >> 4;  // edge offset within 4-edge group
#pragma unroll 1
    for (int c = 0; c < 4; c++) {
#pragma unroll
        for (int jp = 0; jp < 16; jp++) tr[wave][jp][lane] = out[c * 16 + jp];
        __syncthreads();
#pragma unroll 1
        for (int eb = 0; eb < 64; eb += 4) {
            const float v = tr[wave][ch][eb + eo];
            const int rowb = dstsh[wave][eb + eo];
            if (rowb >= 0) unsafeAtomicAdd(accum + rowb + c * 16 + ch, v);
        }
        __syncthreads();
    }
}

// One thread per node: inp = [pos(2), h(64), sum_u(64), sum_h(64)] (194)
// out = tanh(leaky(inp@W1+b1)@W2+b2).  NOTE: sum_h aliases outp (d_out reuse);
// safe because thread n reads only row n before writing row n.
__global__ __launch_bounds__(256, 2) void node_update(
    const float* __restrict__ pos_s, const float* __restrict__ h,
    const float* __restrict__ sum_u, const float* sum_h,
    const float* __restrict__ W1,  // [194,32]
    const float* __restrict__ b1, const float* __restrict__ W2,
    const float* __restrict__ b2, float* outp, int N) {
    const int n = blockIdx.x * 256 + threadIdx.x;
    if (n >= N) return;

    float hid[32];
#pragma unroll
    for (int j = 0; j < 32; j++) hid[j] = b1[j];

    {
        const float p0 = pos_s[2 * n], p1 = pos_s[2 * n + 1];
#pragma unroll
        for (int j = 0; j < 32; j++) hid[j] += p0 * W1[j] + p1 * W1[32 + j];
    }

    const float4* hp = reinterpret_cast<const float4*>(h + n * 64);
#pragma unroll
    for (int c = 0; c < 16; c++) {
        const float4 v = hp[c];
        const float* w = W1 + (2 + 4 * c) * 32;
#pragma unroll
        for (int j = 0; j < 32; j++) {
            hid[j] += v.x * w[j];
            hid[j] += v.y * w[32 + j];
            hid[j] += v.z * w[64 + j];
            hid[j] += v.w * w[96 + j];
        }
    }
    const float4* up = reinterpret_cast<const float4*>(sum_u + n * 64);
#pragma unroll
    for (int c = 0; c < 16; c++) {
        const float4 v = up[c];
        const float* w = W1 + (66 + 4 * c) * 32;
#pragma unroll
        for (int j = 0; j < 32; j++) {
            hid[j] += v.x * w[j];
            hid[j] += v.y * w[32 + j];
            hid[j] += v.z * w[64 + j];
            hid[j] += v.w * w[96 + j];
        }
    }
    const float4* sp = reinterpret_cast<const float4*>(sum_h + n * 64);
#pragma unroll
    for (int c = 0; c < 16; c++) {
        const float4 v = sp[c];
        const float* w = W1 + (130 + 4 * c) * 32;
#pragma unroll
        for (int j = 0; j < 32; j++) {
            hid[j] += v.x * w[j];
            hid[j] += v.y * w[32 + j];
            hid[j] += v.z * w[64 + j];
            hid[j] += v.w * w[96 + j];
        }
    }
#pragma unroll
    for (int j = 0; j < 32; j++) hid[j] = leaky(hid[j]);

    float out[64];
#pragma unroll
    for (int j = 0; j < 64; j++) out[j] = b2[j];
#pragma unroll
    for (int k = 0; k < 32; k++) {
        const float v = hid[k];
        const float* w = W2 + k * 64;
#pragma unroll
        for (int j = 0; j < 64; j++) out[j] += v * w[j];
    }

    float4* op = reinterpret_cast<float4*>(outp + n * 64);
#pragma unroll
    for (int c = 0; c < 16; c++) {
        float4 v;
        v.x = fast_tanh(out[4 * c + 0]);
        v.y = fast_tanh(out[4 * c + 1]);
        v.z = fast_tanh(out[4 * c + 2]);
        v.w = fast_tanh(out[4 * c + 3]);
        op[c] = v;
    }
}

extern "C" void kernel_launch(void* const* d_in, const int* in_sizes, int n_in,
                              void* d_out, int out_size, void* d_ws,
                              size_t ws_size, hipStream_t stream) {
    (void)n_in;
    (void)out_size;
    (void)ws_size;
    const float* h = (const float*)d_in[0];
    const float* u = (const float*)d_in[1];
    const float* pos_s = (const float*)d_in[2];
    const float* pos_a = (const float*)d_in[3];
    const float* dis_a2s = (const float*)d_in[4];
    const float* dis_s2s = (const float*)d_in[5];
    const int* a2s_src = (const int*)d_in[6];
    const int* a2s_dst = (const int*)d_in[7];
    const int* s2s_src = (const int*)d_in[8];
    const int* s2s_dst = (const int*)d_in[9];
    const float* a2s_W1 = (const float*)d_in[10];
    const float* a2s_b1 = (const float*)d_in[11];
    const float* a2s_W2 = (const float*)d_in[12];
    const float* a2s_b2 = (const float*)d_in[13];
    const float* s2s_W1 = (const float*)d_in[14];
    const float* s2s_b1 = (const float*)d_in[15];
    const float* s2s_W2 = (const float*)d_in[16];
    const float* s2s_b2 = (const float*)d_in[17];
    const float* upd_W1 = (const float*)d_in[18];
    const float* upd_b1 = (const float*)d_in[19];
    const float* upd_W2 = (const float*)d_in[20];
    const float* upd_b2 = (const float*)d_in[21];

    const int E = in_sizes[6];       // a2s_src count
    const int NS = in_sizes[0] / 64; // h rows

    float* sum_u = (float*)d_ws;   // [NS,64] in workspace
    float* sum_h = (float*)d_out;  // [NS,64] accumulate directly in d_out

    hipMemsetAsync(sum_u, 0, (size_t)NS * 64 * sizeof(float), stream);
    hipMemsetAsync(sum_h, 0, (size_t)NS * 64 * sizeof(float), stream);

    const int eblocks = (E + 255) / 256;
    edge_mlp_scatter<16><<<eblocks, 256, 0, stream>>>(
        pos_a, pos_s, dis_a2s, u, a2s_src, a2s_dst, a2s_W1, a2s_b1, a2s_W2,
        a2s_b2, sum_u, E);
    edge_mlp_scatter<64><<<eblocks, 256, 0, stream>>>(
        pos_s, pos_s, dis_s2s, h, s2s_src, s2s_dst, s2s_W1, s2s_b1, s2s_W2,
        s2s_b2, sum_h, E);

    const int nblocks = (NS + 255) / 256;
    node_update<<<nblocks, 256, 0, stream>>>(pos_s, h, sum_u, sum_h, upd_W1,
                                             upd_b1, upd_W2, upd_b2,
                                             (float*)d_out, NS);
}